// Round 2
// baseline (641.491 us; speedup 1.0000x reference)
//
#include <hip/hip_runtime.h>
#include <hip/hip_bf16.h>
#include <math.h>

// Problem constants (from reference)
#define VDIM 50000   // K (vocab / nodeNum)
#define BDIM 1024    // M (batch)
#define EDIM 256     // N (embedding)
#define LDIM 17      // Huffman path length

// GEMM tiling
constexpr int BM = 128, BN = 128, BK = 32;
constexpr int LDK = 40;   // padded LDS k-stride; LDK%8==0 keeps ds_read_b128 16B-aligned
constexpr int KT_TOTAL = (VDIM + BK - 1) / BK;  // 1563 k-tiles (last has 16 valid)
constexpr int SPLITS = 64;                      // split-K factor (interleaved) -> grid 1024 = 4 blocks/CU

typedef short bf16x8 __attribute__((ext_vector_type(8)));  // 8 bf16 (4 VGPRs)
typedef float f32x4  __attribute__((ext_vector_type(4)));

// Split one float4 into packed bf16 hi (2x uint32) and bf16 lo (2x uint32).
// hi = truncate-to-bf16(v); lo = truncate-to-bf16(v - hi); total error <= 2^-16 |v|.
__device__ __forceinline__ void split4(const float4 v, uint32_t hi[2], uint32_t lo[2]) {
    const uint32_t ux = __float_as_uint(v.x), uy = __float_as_uint(v.y),
                   uz = __float_as_uint(v.z), uw = __float_as_uint(v.w);
    const uint32_t hx = ux & 0xFFFF0000u, hy = uy & 0xFFFF0000u,
                   hz = uz & 0xFFFF0000u, hw = uw & 0xFFFF0000u;
    const float lx = v.x - __uint_as_float(hx);
    const float ly = v.y - __uint_as_float(hy);
    const float lz = v.z - __uint_as_float(hz);
    const float lw = v.w - __uint_as_float(hw);
    hi[0] = (hx >> 16) | hy;
    hi[1] = (hz >> 16) | hw;
    lo[0] = (__float_as_uint(lx) >> 16) | (__float_as_uint(ly) & 0xFFFF0000u);
    lo[1] = (__float_as_uint(lz) >> 16) | (__float_as_uint(lw) & 0xFFFF0000u);
}

// emb_partial = x @ W^T accumulated via split-K atomics.
// bf16 split-3: A=Ah+Al, B=Bh+Bl; C ~= Ah*Bh + Ah*Bl + Al*Bh.
__global__ __launch_bounds__(256, 4) void gemm_split3(
    const float* __restrict__ X, const float* __restrict__ Wm, float* __restrict__ emb) {
    __shared__ ushort sAhi[BM * LDK];
    __shared__ ushort sAlo[BM * LDK];
    __shared__ ushort sBhi[BN * LDK];
    __shared__ ushort sBlo[BN * LDK];

    const int tid = threadIdx.x;
    const int bn0 = blockIdx.x * BN;          // E offset
    const int bm0 = blockIdx.y * BM;          // B offset
    const int z   = blockIdx.z;               // split index; tiles z, z+SPLITS, ...

    const int lane = tid & 63;
    const int wv   = tid >> 6;                // wave 0..3
    const int wm0  = (wv >> 1) * 64;          // wave tile origin in block tile
    const int wn0  = (wv & 1) * 64;
    const int lm   = lane & 15;               // A/B fragment row (m or n)
    const int lk   = (lane >> 4) * 8;         // fragment k-offset (8 bf16 per lane)

    f32x4 acc[4][4] = {};                     // 4x4 subtiles of 16x16, fp32

    // staging map: 256 threads cover 128 rows x 8 float4-chunks in 4 passes
    const int sr = tid >> 3;                  // row 0..31 (+32 per pass)
    const int sc = (tid & 7) * 4;             // k-col offset within tile (multiple of 4)

    float4 va[4], vb[4];                      // register prefetch buffer (next tile)

    // prologue: load first tile into regs
    int kt = z;
    if (kt < KT_TOTAL) {
        const int k0 = kt * BK;
        const int gk = k0 + sc;
#pragma unroll
        for (int p = 0; p < 4; ++p) {
            const int r = sr + p * 32;
            va[p] = make_float4(0.f, 0.f, 0.f, 0.f);
            vb[p] = va[p];
            if (gk < VDIM) {                  // VDIM%4==0 -> float4 all-or-nothing
                va[p] = *reinterpret_cast<const float4*>(X  + (size_t)(bm0 + r) * VDIM + gk);
                vb[p] = *reinterpret_cast<const float4*>(Wm + (size_t)(bn0 + r) * VDIM + gk);
            }
        }
    }

    for (; kt < KT_TOTAL; kt += SPLITS) {
        __syncthreads();                      // previous iter's LDS reads done
#pragma unroll
        for (int p = 0; p < 4; ++p) {
            const int r = sr + p * 32;
            uint32_t hi[2], lo[2];
            split4(va[p], hi, lo);
            *reinterpret_cast<uint2*>(&sAhi[r * LDK + sc]) = make_uint2(hi[0], hi[1]);
            *reinterpret_cast<uint2*>(&sAlo[r * LDK + sc]) = make_uint2(lo[0], lo[1]);
            split4(vb[p], hi, lo);
            *reinterpret_cast<uint2*>(&sBhi[r * LDK + sc]) = make_uint2(hi[0], hi[1]);
            *reinterpret_cast<uint2*>(&sBlo[r * LDK + sc]) = make_uint2(lo[0], lo[1]);
        }
        __syncthreads();

        // prefetch next tile's global data; vmcnt wait lands after the MFMAs
        const int ktn = kt + SPLITS;
        if (ktn < KT_TOTAL) {
            const int gk = ktn * BK + sc;
#pragma unroll
            for (int p = 0; p < 4; ++p) {
                const int r = sr + p * 32;
                float4 ta = make_float4(0.f, 0.f, 0.f, 0.f), tb = ta;
                if (gk < VDIM) {
                    ta = *reinterpret_cast<const float4*>(X  + (size_t)(bm0 + r) * VDIM + gk);
                    tb = *reinterpret_cast<const float4*>(Wm + (size_t)(bn0 + r) * VDIM + gk);
                }
                va[p] = ta; vb[p] = tb;
            }
        }

        bf16x8 ah[4], al[4], bh[4], bl[4];
#pragma unroll
        for (int mi = 0; mi < 4; ++mi) {
            const int row = wm0 + mi * 16 + lm;
            ah[mi] = *reinterpret_cast<const bf16x8*>(&sAhi[row * LDK + lk]);
            al[mi] = *reinterpret_cast<const bf16x8*>(&sAlo[row * LDK + lk]);
        }
#pragma unroll
        for (int ni = 0; ni < 4; ++ni) {
            const int row = wn0 + ni * 16 + lm;
            bh[ni] = *reinterpret_cast<const bf16x8*>(&sBhi[row * LDK + lk]);
            bl[ni] = *reinterpret_cast<const bf16x8*>(&sBlo[row * LDK + lk]);
        }
#pragma unroll
        for (int mi = 0; mi < 4; ++mi)
#pragma unroll
            for (int ni = 0; ni < 4; ++ni) {
                acc[mi][ni] = __builtin_amdgcn_mfma_f32_16x16x32_bf16(ah[mi], bh[ni], acc[mi][ni], 0, 0, 0);
                acc[mi][ni] = __builtin_amdgcn_mfma_f32_16x16x32_bf16(ah[mi], bl[ni], acc[mi][ni], 0, 0, 0);
                acc[mi][ni] = __builtin_amdgcn_mfma_f32_16x16x32_bf16(al[mi], bh[ni], acc[mi][ni], 0, 0, 0);
            }
    }

    // epilogue: C/D layout col = lane&15, row = (lane>>4)*4 + reg  [m89/m91-verified]
    const int orow = (lane >> 4) * 4;
#pragma unroll
    for (int mi = 0; mi < 4; ++mi)
#pragma unroll
        for (int ni = 0; ni < 4; ++ni)
#pragma unroll
            for (int r = 0; r < 4; ++r) {
                const int gm = bm0 + wm0 + mi * 16 + orow + r;
                const int gn = bn0 + wn0 + ni * 16 + lm;
                atomicAdd(&emb[gm * EDIM + gn], acc[mi][ni][r]);
            }
}

// Stage 2: per batch row b, out[b] = prod_l sigmoid( sign_l * <pv[b,l,:], emb[b,:]+bias> )
__global__ __launch_bounds__(256) void stage2_kernel(
    const float* __restrict__ emb, const float* __restrict__ bias,
    const float* __restrict__ pv, const int* __restrict__ signs,
    float* __restrict__ out) {
    const int b = blockIdx.x;
    __shared__ float se[EDIM];
    __shared__ float wp[4];
    const int t = threadIdx.x;
    se[t] = emb[b * EDIM + t] + bias[t];
    __syncthreads();
    const int w = t >> 6, lane = t & 63;
    float p = 1.0f;
    for (int l = w; l < LDIM; l += 4) {       // wave 0: l=0,4,8,12,16; waves 1-3: 4 each
        const float4 a = *reinterpret_cast<const float4*>(&pv[((size_t)b * LDIM + l) * EDIM + lane * 4]);
        const float4 e = *reinterpret_cast<const float4*>(&se[lane * 4]);
        float d = a.x * e.x + a.y * e.y + a.z * e.z + a.w * e.w;
#pragma unroll
        for (int off = 32; off > 0; off >>= 1) d += __shfl_xor(d, off, 64);
        const float z = signs[b * LDIM + l] ? d : -d;
        p *= 1.0f / (1.0f + expf(-z));
    }
    if (lane == 0) wp[w] = p;
    __syncthreads();
    if (t == 0) out[b] = wp[0] * wp[1] * wp[2] * wp[3];
}

extern "C" void kernel_launch(void* const* d_in, const int* in_sizes, int n_in,
                              void* d_out, int out_size, void* d_ws, size_t ws_size,
                              hipStream_t stream) {
    const float* X    = (const float*)d_in[0];   // [B, V]
    const float* Wm   = (const float*)d_in[1];   // [E, V]
    const float* bias = (const float*)d_in[2];   // [E]
    const float* pv   = (const float*)d_in[3];   // [B, L, E]
    const int*   sg   = (const int*)d_in[4];     // [B, L]
    float* out = (float*)d_out;                  // [B]
    float* emb = (float*)d_ws;                   // [B, E] fp32 accumulator (1 MB)

    hipMemsetAsync(emb, 0, (size_t)BDIM * EDIM * sizeof(float), stream);

    dim3 grid(EDIM / BN, BDIM / BM, SPLITS);     // 2 x 8 x 64 = 1024 blocks
    gemm_split3<<<grid, 256, 0, stream>>>(X, Wm, emb);

    stage2_kernel<<<BDIM, 256, 0, stream>>>(emb, bias, pv, sg, out);
}

// Round 3
// 423.020 us; speedup vs baseline: 1.5165x; 1.5165x over previous
//
#include <hip/hip_runtime.h>
#include <hip/hip_bf16.h>
#include <math.h>

// Problem constants (from reference)
#define VDIM 50000   // K (vocab / nodeNum)
#define BDIM 1024    // M (batch)
#define EDIM 256     // N (embedding)
#define LDIM 17      // Huffman path length

constexpr int BM = 128, BN = 128, BK = 32;
constexpr int KT_FULL = VDIM / BK;            // 1562 full k-tiles
constexpr int SPLITS  = 64;                   // interleaved split-K -> grid 1024
constexpr int TAILZ   = KT_FULL % SPLITS;     // 26: split owning the 16-col tail tile

typedef short bf16x8 __attribute__((ext_vector_type(8)));  // 8 bf16 (4 VGPRs)
typedef float f32x4  __attribute__((ext_vector_type(4)));

// async global->LDS, 16 B per lane; LDS dest = wave-uniform base + lane*16
__device__ __forceinline__ void async_f4(const float* g, float* l) {
    __builtin_amdgcn_global_load_lds(
        (const __attribute__((address_space(1))) void*)g,
        (__attribute__((address_space(3))) void*)l, 16, 0, 0);
}

// 8 consecutive fp32 -> bf16 hi fragment + bf16 lo fragment.
// hi = truncate(f); lo = truncate(f - hi); total error <= 2^-16 |f|.
__device__ __forceinline__ void split8(const float4 f0, const float4 f1, bf16x8& h, bf16x8& l) {
    const float f[8] = {f0.x, f0.y, f0.z, f0.w, f1.x, f1.y, f1.z, f1.w};
#pragma unroll
    for (int i = 0; i < 8; ++i) {
        const uint32_t u  = __float_as_uint(f[i]);
        h[i] = (short)(u >> 16);
        const float lo = f[i] - __uint_as_float(u & 0xFFFF0000u);
        l[i] = (short)(__float_as_uint(lo) >> 16);
    }
}

// emb_partial = x @ W^T via split-K atomics; bf16 split-3 (Ah*Bh + Ah*Bl + Al*Bh).
// LDS holds raw fp32 tiles staged by global_load_lds with XOR-swizzled source
// columns: LDS[row][g*4..] = global[row][( g ^ (row&7) )*4..]  (no padding allowed).
__global__ __launch_bounds__(256) void gemm_split3(
    const float* __restrict__ X, const float* __restrict__ Wm, float* __restrict__ emb) {
    __shared__ __align__(16) float sA[BM * BK];   // 16 KB
    __shared__ __align__(16) float sB[BN * BK];   // 16 KB

    const int tid = threadIdx.x;
    const int bn0 = blockIdx.x * BN;          // E offset
    const int bm0 = blockIdx.y * BM;          // B offset
    const int z   = blockIdx.z;               // split: tiles z, z+SPLITS, ...

    const int lane = tid & 63;
    const int wv   = tid >> 6;                // wave 0..3
    const int wm0  = (wv >> 1) * 64;          // wave tile origin
    const int wn0  = (wv & 1) * 64;
    const int lm   = lane & 15;               // fragment m/n index
    const int gk0  = (lane >> 4) * 2;         // first 4-float group of this lane's k-slice (k = gk0*4)

    // staging geometry: each wave-instruction deposits 8 rows x 32 floats (1 KB)
    const int rsub   = lane >> 3;             // row within 8-row chunk; == row&7
    const int grp    = lane & 7;              // LDS 4-float group this lane fills
    const int coloff = ((grp ^ rsub) << 2);   // swizzled source column within tile
    const int rowS   = wv * 32 + rsub;        // + j*8, j=0..3

    f32x4 acc[4][4] = {};

    auto compute = [&]() {
        bf16x8 ah[4], al[4];
#pragma unroll
        for (int mi = 0; mi < 4; ++mi) {
            const int row = wm0 + mi * 16 + lm;
            const int s = row & 7;
            const float4 f0 = *reinterpret_cast<const float4*>(&sA[row * BK + ((gk0 ^ s) << 2)]);
            const float4 f1 = *reinterpret_cast<const float4*>(&sA[row * BK + (((gk0 + 1) ^ s) << 2)]);
            split8(f0, f1, ah[mi], al[mi]);
        }
#pragma unroll
        for (int ni = 0; ni < 4; ++ni) {
            const int row = wn0 + ni * 16 + lm;
            const int s = row & 7;
            const float4 f0 = *reinterpret_cast<const float4*>(&sB[row * BK + ((gk0 ^ s) << 2)]);
            const float4 f1 = *reinterpret_cast<const float4*>(&sB[row * BK + (((gk0 + 1) ^ s) << 2)]);
            bf16x8 bh, bl;
            split8(f0, f1, bh, bl);
#pragma unroll
            for (int mi = 0; mi < 4; ++mi) {
                acc[mi][ni] = __builtin_amdgcn_mfma_f32_16x16x32_bf16(ah[mi], bh, acc[mi][ni], 0, 0, 0);
                acc[mi][ni] = __builtin_amdgcn_mfma_f32_16x16x32_bf16(ah[mi], bl, acc[mi][ni], 0, 0, 0);
                acc[mi][ni] = __builtin_amdgcn_mfma_f32_16x16x32_bf16(al[mi], bh, acc[mi][ni], 0, 0, 0);
            }
        }
    };

    for (int kt = z; kt < KT_FULL; kt += SPLITS) {
        const int k0 = kt * BK;
        __syncthreads();                      // previous iter's LDS reads done
#pragma unroll
        for (int j = 0; j < 4; ++j) {
            const int row = rowS + j * 8;
            async_f4(X  + (size_t)(bm0 + row) * VDIM + k0 + coloff, &sA[(wv * 32 + j * 8) * BK]);
            async_f4(Wm + (size_t)(bn0 + row) * VDIM + k0 + coloff, &sB[(wv * 32 + j * 8) * BK]);
        }
        __syncthreads();                      // vmcnt(0) drain -> tiles ready
        compute();
    }

    if (z == TAILZ) {                         // tail tile kt=1562: cols 49984..49999 valid
        const int k0 = KT_FULL * BK;
        __syncthreads();
#pragma unroll
        for (int j = 0; j < 4; ++j) {
            const int row = rowS + j * 8;
            float4 va = make_float4(0.f, 0.f, 0.f, 0.f), vb = va;
            if (coloff < 16) {                // groups beyond K-remainder stay zero
                va = *reinterpret_cast<const float4*>(X  + (size_t)(bm0 + row) * VDIM + k0 + coloff);
                vb = *reinterpret_cast<const float4*>(Wm + (size_t)(bn0 + row) * VDIM + k0 + coloff);
            }
            // same LDS bytes the async path would write: base + lane*16
            *reinterpret_cast<float4*>(&sA[row * BK + (grp << 2)]) = va;
            *reinterpret_cast<float4*>(&sB[row * BK + (grp << 2)]) = vb;
        }
        __syncthreads();
        compute();                            // zero-padded cols contribute 0
    }

    // epilogue: C/D layout col = lane&15, row = (lane>>4)*4 + reg  [m89/m91-verified]
    const int orow = (lane >> 4) * 4;
#pragma unroll
    for (int mi = 0; mi < 4; ++mi)
#pragma unroll
        for (int ni = 0; ni < 4; ++ni)
#pragma unroll
            for (int r = 0; r < 4; ++r) {
                const int gm = bm0 + wm0 + mi * 16 + orow + r;
                const int gn = bn0 + wn0 + ni * 16 + lm;
                atomicAdd(&emb[gm * EDIM + gn], acc[mi][ni][r]);
            }
}

// Stage 2: per batch row b, out[b] = prod_l sigmoid( sign_l * <pv[b,l,:], emb[b,:]+bias> )
__global__ __launch_bounds__(256) void stage2_kernel(
    const float* __restrict__ emb, const float* __restrict__ bias,
    const float* __restrict__ pv, const int* __restrict__ signs,
    float* __restrict__ out) {
    const int b = blockIdx.x;
    __shared__ float se[EDIM];
    __shared__ float wp[4];
    const int t = threadIdx.x;
    se[t] = emb[b * EDIM + t] + bias[t];
    __syncthreads();
    const int w = t >> 6, lane = t & 63;
    float p = 1.0f;
    for (int l = w; l < LDIM; l += 4) {
        const float4 a = *reinterpret_cast<const float4*>(&pv[((size_t)b * LDIM + l) * EDIM + lane * 4]);
        const float4 e = *reinterpret_cast<const float4*>(&se[lane * 4]);
        float d = a.x * e.x + a.y * e.y + a.z * e.z + a.w * e.w;
#pragma unroll
        for (int off = 32; off > 0; off >>= 1) d += __shfl_xor(d, off, 64);
        const float zz = signs[b * LDIM + l] ? d : -d;
        p *= 1.0f / (1.0f + expf(-zz));
    }
    if (lane == 0) wp[w] = p;
    __syncthreads();
    if (t == 0) out[b] = wp[0] * wp[1] * wp[2] * wp[3];
}

extern "C" void kernel_launch(void* const* d_in, const int* in_sizes, int n_in,
                              void* d_out, int out_size, void* d_ws, size_t ws_size,
                              hipStream_t stream) {
    const float* X    = (const float*)d_in[0];   // [B, V]
    const float* Wm   = (const float*)d_in[1];   // [E, V]
    const float* bias = (const float*)d_in[2];   // [E]
    const float* pv   = (const float*)d_in[3];   // [B, L, E]
    const int*   sg   = (const int*)d_in[4];     // [B, L]
    float* out = (float*)d_out;                  // [B]
    float* emb = (float*)d_ws;                   // [B, E] fp32 accumulator (1 MB)

    hipMemsetAsync(emb, 0, (size_t)BDIM * EDIM * sizeof(float), stream);

    dim3 grid(EDIM / BN, BDIM / BM, SPLITS);     // 2 x 8 x 64 = 1024 blocks
    gemm_split3<<<grid, 256, 0, stream>>>(X, Wm, emb);

    stage2_kernel<<<BDIM, 256, 0, stream>>>(emb, bias, pv, sg, out);
}

// Round 4
// 398.668 us; speedup vs baseline: 1.6091x; 1.0611x over previous
//
#include <hip/hip_runtime.h>
#include <hip/hip_bf16.h>
#include <math.h>

// Problem constants (from reference)
#define VDIM 50000   // K (vocab / nodeNum)
#define BDIM 1024    // M (batch)
#define EDIM 256     // N (embedding)
#define LDIM 17      // Huffman path length

constexpr int BM = 128, BN = 128, BK = 32;
constexpr int KT_FULL = VDIM / BK;            // 1562 full k-tiles
constexpr int SPLITS  = 32;                   // interleaved split-K -> grid 512 = 2 blocks/CU
constexpr int TAILZ   = KT_FULL % SPLITS;     // 26: split owning the 16-col tail tile

typedef short bf16x8 __attribute__((ext_vector_type(8)));  // 8 bf16 (4 VGPRs)
typedef float f32x4  __attribute__((ext_vector_type(4)));

// async global->LDS, 16 B per lane; LDS dest = wave-uniform base + lane*16
__device__ __forceinline__ void async_f4(const float* g, float* l) {
    __builtin_amdgcn_global_load_lds(
        (const __attribute__((address_space(1))) void*)g,
        (__attribute__((address_space(3))) void*)l, 16, 0, 0);
}

// 8 consecutive fp32 -> bf16 hi fragment + bf16 lo fragment.
// hi = truncate(f); lo = truncate(f - hi); total error <= 2^-16 |f|.
__device__ __forceinline__ void split8(const float4 f0, const float4 f1, bf16x8& h, bf16x8& l) {
    const float f[8] = {f0.x, f0.y, f0.z, f0.w, f1.x, f1.y, f1.z, f1.w};
#pragma unroll
    for (int i = 0; i < 8; ++i) {
        const uint32_t u  = __float_as_uint(f[i]);
        h[i] = (short)(u >> 16);
        const float lo = f[i] - __uint_as_float(u & 0xFFFF0000u);
        l[i] = (short)(__float_as_uint(lo) >> 16);
    }
}

// emb_partial = x @ W^T via split-K atomics; bf16 split-3 (Ah*Bh + Ah*Bl + Al*Bh).
// Double-buffered LDS pipeline: loads for tile t+1 issued right after the barrier
// publishing tile t, so the next barrier's vmcnt(0) drain lands after ~1300 cyc of
// compute (> HBM latency) instead of immediately after issue.
// LDS holds raw fp32 tiles (global_load_lds, XOR-swizzled source columns:
// LDS[row][g*4..] = global[row][(g ^ (row&7))*4..]; no padding allowed).
__global__ __launch_bounds__(256) void gemm_split3(
    const float* __restrict__ X, const float* __restrict__ Wm, float* __restrict__ emb) {
    __shared__ __align__(16) float sA[2][BM * BK];   // 2 x 16 KB
    __shared__ __align__(16) float sB[2][BN * BK];   // 2 x 16 KB

    const int tid = threadIdx.x;
    const int bn0 = blockIdx.x * BN;          // E offset
    const int bm0 = blockIdx.y * BM;          // B offset
    const int z   = blockIdx.z;               // split: tiles z, z+SPLITS, ...

    const int lane = tid & 63;
    const int wv   = tid >> 6;                // wave 0..3
    const int wm0  = (wv >> 1) * 64;          // wave tile origin
    const int wn0  = (wv & 1) * 64;
    const int lm   = lane & 15;               // fragment m/n index
    const int gk0  = (lane >> 4) * 2;         // first 4-float group of this lane's k-slice

    // staging geometry: each wave-instruction deposits 8 rows x 32 floats (1 KB)
    const int rsub   = lane >> 3;             // row within 8-row chunk; == row&7
    const int grp    = lane & 7;              // LDS 4-float group this lane fills
    const int coloff = ((grp ^ rsub) << 2);   // swizzled source column within tile
    const int rowS   = wv * 32 + rsub;        // + j*8, j=0..3

    f32x4 acc[4][4] = {};

    auto issue = [&](int kt, int pb) {
        const int k0 = kt * BK;
#pragma unroll
        for (int j = 0; j < 4; ++j) {
            const int row = rowS + j * 8;
            async_f4(X  + (size_t)(bm0 + row) * VDIM + k0 + coloff, &sA[pb][(wv * 32 + j * 8) * BK]);
            async_f4(Wm + (size_t)(bn0 + row) * VDIM + k0 + coloff, &sB[pb][(wv * 32 + j * 8) * BK]);
        }
    };

    auto compute = [&](int pb) {
        const float* A = sA[pb];
        const float* Bs = sB[pb];
        bf16x8 ah[4], al[4];
#pragma unroll
        for (int mi = 0; mi < 4; ++mi) {
            const int row = wm0 + mi * 16 + lm;
            const int s = row & 7;
            const float4 f0 = *reinterpret_cast<const float4*>(&A[row * BK + ((gk0 ^ s) << 2)]);
            const float4 f1 = *reinterpret_cast<const float4*>(&A[row * BK + (((gk0 + 1) ^ s) << 2)]);
            split8(f0, f1, ah[mi], al[mi]);
        }
#pragma unroll
        for (int ni = 0; ni < 4; ++ni) {
            const int row = wn0 + ni * 16 + lm;
            const int s = row & 7;
            const float4 f0 = *reinterpret_cast<const float4*>(&Bs[row * BK + ((gk0 ^ s) << 2)]);
            const float4 f1 = *reinterpret_cast<const float4*>(&Bs[row * BK + (((gk0 + 1) ^ s) << 2)]);
            bf16x8 bh, bl;
            split8(f0, f1, bh, bl);
#pragma unroll
            for (int mi = 0; mi < 4; ++mi) {
                acc[mi][ni] = __builtin_amdgcn_mfma_f32_16x16x32_bf16(ah[mi], bh, acc[mi][ni], 0, 0, 0);
                acc[mi][ni] = __builtin_amdgcn_mfma_f32_16x16x32_bf16(ah[mi], bl, acc[mi][ni], 0, 0, 0);
                acc[mi][ni] = __builtin_amdgcn_mfma_f32_16x16x32_bf16(al[mi], bh, acc[mi][ni], 0, 0, 0);
            }
        }
    };

    // pipelined main loop over this split's tiles
    int pb = 0;
    issue(z, 0);                              // prologue: first tile into buf 0
    for (int kt = z + SPLITS; kt < KT_FULL; kt += SPLITS) {
        __syncthreads();                      // drains vmcnt -> buf pb ready; buf pb^1 free
        issue(kt, pb ^ 1);                    // prefetch next tile (in flight across compute)
        compute(pb);
        pb ^= 1;
    }
    __syncthreads();                          // last tile's loads drained
    compute(pb);

    if (z == TAILZ) {                         // tail tile kt=1562: cols 49984..49999 valid
        const int k0 = KT_FULL * BK;
#pragma unroll
        for (int j = 0; j < 4; ++j) {
            const int row = rowS + j * 8;
            float4 va = make_float4(0.f, 0.f, 0.f, 0.f), vb = va;
            if (coloff < 16) {                // groups beyond K-remainder stay zero
                va = *reinterpret_cast<const float4*>(X  + (size_t)(bm0 + row) * VDIM + k0 + coloff);
                vb = *reinterpret_cast<const float4*>(Wm + (size_t)(bn0 + row) * VDIM + k0 + coloff);
            }
            // same LDS bytes the async path would write: base + lane*16
            *reinterpret_cast<float4*>(&sA[pb ^ 1][row * BK + (grp << 2)]) = va;
            *reinterpret_cast<float4*>(&sB[pb ^ 1][row * BK + (grp << 2)]) = vb;
        }
        __syncthreads();
        compute(pb ^ 1);                      // zero-padded cols contribute 0
    }

    // epilogue: C/D layout col = lane&15, row = (lane>>4)*4 + reg  [m89/m91-verified]
    const int orow = (lane >> 4) * 4;
#pragma unroll
    for (int mi = 0; mi < 4; ++mi)
#pragma unroll
        for (int ni = 0; ni < 4; ++ni)
#pragma unroll
            for (int r = 0; r < 4; ++r) {
                const int gm = bm0 + wm0 + mi * 16 + orow + r;
                const int gn = bn0 + wn0 + ni * 16 + lm;
                atomicAdd(&emb[gm * EDIM + gn], acc[mi][ni][r]);
            }
}

// Stage 2: per batch row b, out[b] = prod_l sigmoid( sign_l * <pv[b,l,:], emb[b,:]+bias> )
__global__ __launch_bounds__(256) void stage2_kernel(
    const float* __restrict__ emb, const float* __restrict__ bias,
    const float* __restrict__ pv, const int* __restrict__ signs,
    float* __restrict__ out) {
    const int b = blockIdx.x;
    __shared__ float se[EDIM];
    __shared__ float wp[4];
    const int t = threadIdx.x;
    se[t] = emb[b * EDIM + t] + bias[t];
    __syncthreads();
    const int w = t >> 6, lane = t & 63;
    float p = 1.0f;
    for (int l = w; l < LDIM; l += 4) {
        const float4 a = *reinterpret_cast<const float4*>(&pv[((size_t)b * LDIM + l) * EDIM + lane * 4]);
        const float4 e = *reinterpret_cast<const float4*>(&se[lane * 4]);
        float d = a.x * e.x + a.y * e.y + a.z * e.z + a.w * e.w;
#pragma unroll
        for (int off = 32; off > 0; off >>= 1) d += __shfl_xor(d, off, 64);
        const float zz = signs[b * LDIM + l] ? d : -d;
        p *= 1.0f / (1.0f + expf(-zz));
    }
    if (lane == 0) wp[w] = p;
    __syncthreads();
    if (t == 0) out[b] = wp[0] * wp[1] * wp[2] * wp[3];
}

extern "C" void kernel_launch(void* const* d_in, const int* in_sizes, int n_in,
                              void* d_out, int out_size, void* d_ws, size_t ws_size,
                              hipStream_t stream) {
    const float* X    = (const float*)d_in[0];   // [B, V]
    const float* Wm   = (const float*)d_in[1];   // [E, V]
    const float* bias = (const float*)d_in[2];   // [E]
    const float* pv   = (const float*)d_in[3];   // [B, L, E]
    const int*   sg   = (const int*)d_in[4];     // [B, L]
    float* out = (float*)d_out;                  // [B]
    float* emb = (float*)d_ws;                   // [B, E] fp32 accumulator (1 MB)

    hipMemsetAsync(emb, 0, (size_t)BDIM * EDIM * sizeof(float), stream);

    dim3 grid(EDIM / BN, BDIM / BM, SPLITS);     // 2 x 8 x 32 = 512 blocks
    gemm_split3<<<grid, 256, 0, stream>>>(X, Wm, emb);

    stage2_kernel<<<BDIM, 256, 0, stream>>>(emb, bias, pv, sg, out);
}